// Round 14
// baseline (58.495 us; speedup 1.0000x reference)
//
#include <hip/hip_runtime.h>

#define B_DIM   16384
#define T_DIM   50
#define F_DIM   128
#define NSPLIT  63
#define LEAVES  64
#define DEPTHM1 6
#define PROB_SZ (B_DIM * T_DIM * 2)

#define WPB   4                    // waves per block
#define BLOCK (WPB * 64)           // 256
#define GRID  (B_DIM / (WPB * 2))  // 2048: each wave owns a b-pair (VERIFIED mapping)

typedef float vf2 __attribute__((ext_vector_type(2)));
typedef float vf4 __attribute__((ext_vector_type(4)));

// Kernel 1: one-hot masks -> u8 feature index, padded rows [T_DIM][64].
__global__ __launch_bounds__(256)
void build_tables(const float* __restrict__ masks, unsigned char* __restrict__ idx) {
    __shared__ float m_l[F_DIM * NSPLIT];   // 32.2 KB
    const int t = blockIdx.x;
    const float* src = masks + (size_t)t * (F_DIM * NSPLIT);
    for (int i = threadIdx.x; i < F_DIM * NSPLIT; i += 256) m_l[i] = src[i];
    __syncthreads();
    const int n = threadIdx.x;
    if (n < NSPLIT) {
        int fi = 0;
        for (int f = 0; f < F_DIM; ++f)
            if (m_l[f * NSPLIT + n] != 0.f) fi = f;
        idx[t * 64 + n] = (unsigned char)fi;
    }
}

// Dual-b: both b's of the pair processed together so every LDS access serves
// two outputs (gather b64 instead of 2x b32, pi read once instead of twice).
// waves_per_eu(4,4): 128-VGPR budget, ~105 live -> no squeeze-spill (R8 lesson).
__global__ __launch_bounds__(BLOCK)
__attribute__((amdgpu_waves_per_eu(4, 4)))
void forest_kernel(const float* __restrict__ x, const float* __restrict__ pi,
                   const unsigned char* __restrict__ tbl, float* __restrict__ out) {
    __shared__ float xs[WPB][2 * F_DIM];    //  4.0 KB: [f*2+s] = x_{b+s}[f]
    __shared__ vf2   pi_p[LEAVES * T_DIM];  // 25.6 KB: [l][t]=(pi[t,l,0],pi[t,l,1])
    // total 29.6 KB

    const int tid  = threadIdx.x;
    const int w    = tid >> 6;
    const int lane = tid & 63;
    const int t    = lane;                  // lanes 50..63 idle in compute

    // per-lane idx row -> 16 u32 registers (3.2KB table, L1/L2-resident)
    unsigned int warr[16];
    {
        const uint4* row = (const uint4*)(tbl + (size_t)((t < T_DIM) ? t : 0) * 64);
        uint4 r0 = row[0], r1 = row[1], r2 = row[2], r3 = row[3];
        *(uint4*)&warr[0]  = r0; *(uint4*)&warr[4]  = r1;
        *(uint4*)&warr[8]  = r2; *(uint4*)&warr[12] = r3;
    }
#define IDX(k) ((int)((warr[(k) >> 2] >> (((k) & 3) * 8)) & 127u))

    // pi transpose-stage: global float2 index i = t*64 + l -> LDS [l*50 + t]
    for (int i = tid; i < T_DIM * LEAVES; i += BLOCK) {
        int t2 = i >> 6, l2 = i & 63;
        vf2 q = ((const vf2*)pi)[i];
        pi_p[l2 * T_DIM + t2] = q;
    }
    __syncthreads();   // only block-wide barrier; waves free-run afterwards

    const int b0 = (blockIdx.x * WPB + w) * 2;
    float* xw = xs[w];

    // both x rows, coalesced 512B each; element-interleave into LDS with one
    // b128 per lane (all 64 lanes exactly cover the 1KB row)
    vf2 r0 = *(const vf2*)(x + (size_t)b0 * F_DIM + 2 * lane);
    vf2 r1 = *(const vf2*)(x + (size_t)(b0 + 1) * F_DIM + 2 * lane);
    vf4 wv = {r0.x, r1.x, r0.y, r1.y};
    *(vf4*)(&xw[4 * lane]) = wv;

    if (t < T_DIM) {
        float mu0[LEAVES / 2], mu1[LEAVES / 2];   // 64 regs
        float p00 = 0.f, p01 = 0.f, p10 = 0.f, p11 = 0.f;
        float* dstb0 = out + PROB_SZ + (size_t)b0 * (LEAVES * T_DIM) + t;
        float* dstb1 = dstb0 + LEAVES * T_DIM;
        const vf2* pp = &pi_p[t];

        mu0[0] = 1.f; mu1[0] = 1.f;
        int begin = 0;
        // levels 0..4: one b64 gather feeds BOTH b's sigmoids
#pragma unroll
        for (int level = 0; level < DEPTHM1 - 1; ++level) {
            const int width = 1 << level;
#pragma unroll
            for (int i = width - 1; i >= 0; --i) {
                const int fi = IDX(begin + i);
                vf2 xv = *(const vf2*)(&xw[2 * fi]);      // ds_read_b64
                float e0 = __expf(-xv.x);
                float d0 = __builtin_amdgcn_rcpf(1.f + e0);
                float e1 = __expf(-xv.y);
                float d1 = __builtin_amdgcn_rcpf(1.f + e1);
                float m0 = mu0[i], m1 = mu1[i];
                mu0[2 * i] = m0 * d0; mu0[2 * i + 1] = m0 - mu0[2 * i];
                mu1[2 * i] = m1 * d1; mu1[2 * i + 1] = m1 - mu1[2 * i];
            }
            begin += width;
        }
        // level 5 fused with probs-store + pi-reduction; pi read ONCE per pair
#pragma unroll
        for (int i = 31; i >= 0; --i) {
            const int fi = IDX(31 + i);
            vf2 xv = *(const vf2*)(&xw[2 * fi]);          // ds_read_b64
            float e0 = __expf(-xv.x);
            float d0 = __builtin_amdgcn_rcpf(1.f + e0);
            float e1 = __expf(-xv.y);
            float d1 = __builtin_amdgcn_rcpf(1.f + e1);
            float m0 = mu0[i], m1 = mu1[i];
            float a0 = m0 * d0, c0 = m0 - a0;
            float a1 = m1 * d1, c1 = m1 - a1;
            dstb0[(2 * i)     * T_DIM] = a0;   // contiguous 200B run/inst
            dstb0[(2 * i + 1) * T_DIM] = c0;
            dstb1[(2 * i)     * T_DIM] = a1;
            dstb1[(2 * i + 1) * T_DIM] = c1;
            vf2 q0 = pp[(2 * i)     * T_DIM];  // conflict-free ds_read_b64
            vf2 q1 = pp[(2 * i + 1) * T_DIM];
            p00 += a0 * q0.x + c0 * q1.x;
            p01 += a0 * q0.y + c0 * q1.y;
            p10 += a1 * q0.x + c1 * q1.x;
            p11 += a1 * q0.y + c1 * q1.y;
        }
        ((vf2*)out)[b0 * T_DIM + t]       = (vf2){p00, p01};
        ((vf2*)out)[(b0 + 1) * T_DIM + t] = (vf2){p10, p11};
    }
#undef IDX
}

extern "C" void kernel_launch(void* const* d_in, const int* in_sizes, int n_in,
                              void* d_out, int out_size, void* d_ws, size_t ws_size,
                              hipStream_t stream) {
    const float* x     = (const float*)d_in[0];
    const float* masks = (const float*)d_in[1];
    const float* pi    = (const float*)d_in[2];

    unsigned char* tbl = (unsigned char*)d_ws;
    float* out = (float*)d_out;

    build_tables<<<T_DIM, 256, 0, stream>>>(masks, tbl);
    forest_kernel<<<GRID, BLOCK, 0, stream>>>(x, pi, tbl, out);
}

// Round 16
// 50.391 us; speedup vs baseline: 1.1608x; 1.1608x over previous
//
#include <hip/hip_runtime.h>

#define B_DIM   16384
#define T_DIM   50
#define F_DIM   128
#define NSPLIT  63
#define LEAVES  64
#define DEPTHM1 6
#define PROB_SZ (B_DIM * T_DIM * 2)

#define WPB   4                    // waves per block
#define BLOCK (WPB * 64)           // 256
#define IT    2                    // b's per wave — VERIFIED optimum (R7/R9/R12);
#define GRID  (B_DIM / (WPB * IT)) // 2048  IT=4/persistent/dual-b all regressed

typedef float vf2 __attribute__((ext_vector_type(2)));

// Kernel 1: one-hot masks -> u8 feature index, padded rows [T_DIM][64].
// Pad byte (n=63) is ZEROED so no downstream read ever touches memory this
// kernel didn't write (harness poisons d_ws to 0xAA before timing replays).
__global__ __launch_bounds__(256)
void build_tables(const float* __restrict__ masks, unsigned char* __restrict__ idx) {
    __shared__ float m_l[F_DIM * NSPLIT];   // 32.2 KB
    const int t = blockIdx.x;
    const float* src = masks + (size_t)t * (F_DIM * NSPLIT);
    for (int i = threadIdx.x; i < F_DIM * NSPLIT; i += 256) m_l[i] = src[i];
    __syncthreads();
    const int n = threadIdx.x;
    if (n < NSPLIT) {
        int fi = 0;
        for (int f = 0; f < F_DIM; ++f)
            if (m_l[f * NSPLIT + n] != 0.f) fi = f;
        idx[t * 64 + n] = (unsigned char)fi;
    }
    if (n == NSPLIT) idx[t * 64 + NSPLIT] = 0;   // init pad byte
}

// waves_per_eu(4,5): pin the register allocator to the ~102-VGPR regime.
// R8 lesson: without the max, the compiler squeezed to 64 VGPRs (8 waves/EU)
// and spilled warr[]+mu[] to scratch (+71MB fetch, +43MB write, 2x time).
__global__ __launch_bounds__(BLOCK)
__attribute__((amdgpu_waves_per_eu(4, 5)))
void forest_kernel(const float* __restrict__ x, const float* __restrict__ pi,
                   const unsigned char* __restrict__ tbl, float* __restrict__ out) {
    __shared__ float xs[WPB][F_DIM];        //  2.0 KB (wave-private rows)
    __shared__ vf2   pi_p[LEAVES * T_DIM];  // 25.6 KB: [l][t]=(pi[t,l,0],pi[t,l,1])
    // total 27.6 KB -> 5 blocks/CU

    const int tid  = threadIdx.x;
    const int w    = tid >> 6;
    const int lane = tid & 63;
    const int t    = lane;                  // lanes 50..63 idle in compute

    // per-lane idx row -> 16 u32 registers (once per wave; table is 3.2KB,
    // L1/L2-resident; removes 63 ds_read_u8 from every b-iteration)
    unsigned int warr[16];
    {
        const uint4* row = (const uint4*)(tbl + (size_t)((t < T_DIM) ? t : 0) * 64);
        uint4 r0 = row[0], r1 = row[1], r2 = row[2], r3 = row[3];
        *(uint4*)&warr[0]  = r0; *(uint4*)&warr[4]  = r1;
        *(uint4*)&warr[8]  = r2; *(uint4*)&warr[12] = r3;
    }
#define IDX(k) ((int)((warr[(k) >> 2] >> (((k) & 3) * 8)) & 127u))

    // pi transpose-stage: global float2 index i = t*64 + l -> LDS [l*50 + t]
    for (int i = tid; i < T_DIM * LEAVES; i += BLOCK) {
        int t2 = i >> 6, l2 = i & 63;
        vf2 q = ((const vf2*)pi)[i];
        pi_p[l2 * T_DIM + t2] = q;
    }
    __syncthreads();   // only block-wide barrier; waves free-run afterwards

    const int bw0 = (blockIdx.x * WPB + w) * IT;
    float* xw = xs[w];

    // prologue: first x row -> regs (all 64 lanes, coalesced 512B)
    vf2 xreg = *(const vf2*)(x + (size_t)bw0 * F_DIM + 2 * lane);

    for (int it = 0; it < IT; ++it) {
        const int b = bw0 + it;

        // wave-private LDS write; DS ops in-order vs previous iter's reads
        *(vf2*)(&xw[2 * lane]) = xreg;

        float mu[LEAVES / 2];       // levels 0..4 only (32 regs)
        float p0 = 0.f, p1 = 0.f;
        float* dstb = out + PROB_SZ + (size_t)b * (LEAVES * T_DIM) + t;

        if (t < T_DIM) {
            const vf2* pp = &pi_p[t];

            mu[0] = 1.f;
            int begin = 0;
            // levels 0..4: pure compute, builds mu[0..31]
#pragma unroll
            for (int level = 0; level < DEPTHM1 - 1; ++level) {
                const int width = 1 << level;
#pragma unroll
                for (int i = width - 1; i >= 0; --i) {
                    const int fi = IDX(begin + i);              // v_bfe (no LDS)
                    float xv = xw[fi];                          // ds_read_b32 gather
                    float e  = __expf(-xv);
                    float d  = __builtin_amdgcn_rcpf(1.f + e);
                    float m  = mu[i];
                    mu[2 * i]     = m * d;
                    mu[2 * i + 1] = m - mu[2 * i];
                }
                begin += width;
            }
            // level 5 fused with probs-store + pi-reduction (anti-convoy)
#pragma unroll
            for (int i = 31; i >= 0; --i) {
                const int fi = IDX(31 + i);
                float xv = xw[fi];
                float e  = __expf(-xv);
                float d  = __builtin_amdgcn_rcpf(1.f + e);
                float m  = mu[i];
                float a  = m * d;
                float c2 = m - a;
                dstb[(2 * i)     * T_DIM] = a;     // contiguous 200B run/inst
                dstb[(2 * i + 1) * T_DIM] = c2;
                vf2 q0 = pp[(2 * i)     * T_DIM];  // conflict-free ds_read_b64
                vf2 q1 = pp[(2 * i + 1) * T_DIM];
                p0 += a * q0.x + c2 * q1.x;
                p1 += a * q0.y + c2 * q1.y;
            }
        }

        // prefetch next x row while stores drain (VERIFIED position)
        if (it + 1 < IT)
            xreg = *(const vf2*)(x + (size_t)(b + 1) * F_DIM + 2 * lane);

        if (t < T_DIM)
            ((vf2*)out)[b * T_DIM + t] = (vf2){p0, p1};
    }
#undef IDX
}

extern "C" void kernel_launch(void* const* d_in, const int* in_sizes, int n_in,
                              void* d_out, int out_size, void* d_ws, size_t ws_size,
                              hipStream_t stream) {
    const float* x     = (const float*)d_in[0];
    const float* masks = (const float*)d_in[1];
    const float* pi    = (const float*)d_in[2];

    unsigned char* tbl = (unsigned char*)d_ws;
    float* out = (float*)d_out;

    build_tables<<<T_DIM, 256, 0, stream>>>(masks, tbl);
    forest_kernel<<<GRID, BLOCK, 0, stream>>>(x, pi, tbl, out);
}